// Round 1
// baseline (230.160 us; speedup 1.0000x reference)
//
#include <hip/hip_runtime.h>
#include <hip/hip_bf16.h>

#define NDIM 2048
#define QDIM 1024
#define SDIM 512
#define NBINS 20

// ---------------- K0: softmax prep (probs over calib_w, cw over col_weights)
__global__ void k_prep(const float* __restrict__ calib_w,
                       const float* __restrict__ col_w,
                       float* __restrict__ probs,
                       float* __restrict__ cw) {
  __shared__ float red[256];
  int t = threadIdx.x;
  if (t == 0) {
    float m = -1e30f;
    for (int b = 0; b < NBINS; b++) m = fmaxf(m, calib_w[b]);
    float e[NBINS]; float s = 0.f;
    for (int b = 0; b < NBINS; b++) { e[b] = __expf(calib_w[b] - m); s += e[b]; }
    float inv = 1.0f / s;
    for (int b = 0; b < NBINS; b++) probs[b] = e[b] * inv;
  }
  float lm = -1e30f;
  for (int j = t; j < NDIM; j += 256) lm = fmaxf(lm, col_w[j]);
  red[t] = lm; __syncthreads();
  for (int s = 128; s > 0; s >>= 1) { if (t < s) red[t] = fmaxf(red[t], red[t+s]); __syncthreads(); }
  float gmax = red[0]; __syncthreads();
  float ls = 0.f;
  for (int j = t; j < NDIM; j += 256) ls += __expf(col_w[j] - gmax);
  red[t] = ls; __syncthreads();
  for (int s = 128; s > 0; s >>= 1) { if (t < s) red[t] += red[t+s]; __syncthreads(); }
  float scale = (float)NDIM / red[0];
  for (int j = t; j < NDIM; j += 256) cw[j] = __expf(col_w[j] - gmax) * scale;
}

// ---------------- K1: local calibration (one block per row) + row sums
__global__ __launch_bounds__(256) void k_calib(const float* __restrict__ graph,
                                               const float* __restrict__ probs,
                                               float* __restrict__ g0,
                                               float* __restrict__ rowsum) {
  __shared__ float sp[NBINS];
  __shared__ float red[256];
  int i = blockIdx.x, t = threadIdx.x;
  if (t < NBINS) sp[t] = probs[t];
  __syncthreads();
  const float* row = graph + (size_t)i * NDIM;
  float* orow = g0 + (size_t)i * NDIM;
  float rs = 0.f;
  for (int it = 0; it < NDIM / 256; it++) {
    int j = t + it * 256;
    float g = row[j];
    float v = 0.f;
    if (g > 0.f) {
      float num = 0.f, den = 0.f;
      #pragma unroll
      for (int b = 0; b < NBINS; b++) {
        float d = g - (float)b * (1.0f / 19.0f);
        float z = __expf(-950.0f * d * d);   // sig = (1/19)/50 = 1/950 for all bins
        den += z; num += z * sp[b];
      }
      v = den > 0.f ? num / den : 0.f;
    }
    orow[j] = v;
    rs += v;
  }
  red[t] = rs; __syncthreads();
  for (int s = 128; s > 0; s >>= 1) { if (t < s) red[t] += red[t+s]; __syncthreads(); }
  if (t == 0) rowsum[i] = red[0];
}

// ---------------- K2: column sums of g0
__global__ void k_colsum(const float* __restrict__ g0, float* __restrict__ colsum) {
  int j = blockIdx.x * 256 + threadIdx.x;   // gridDim.x = 8
  int r0 = blockIdx.y * 128;                // gridDim.y = 16
  float s = 0.f;
  for (int r = r0; r < r0 + 128; r++) s += g0[(size_t)r * NDIM + j];
  atomicAdd(&colsum[j], s);
}

// ---------------- K3: per-row/col scale factors
__global__ void k_factors(const float* __restrict__ rowsum, const float* __restrict__ colsum,
                          const float* __restrict__ cw,
                          float* __restrict__ leftv, float* __restrict__ rightc,
                          float* __restrict__ mvec) {
  int j = blockIdx.x * 256 + threadIdx.x;
  float rsum = rowsum[j], csum = colsum[j];
  float l = rsum > 0.f ? 1.0f / sqrtf(rsum) : 0.f;   // divide_no_nan(1, sqrt(.))
  float r = csum > 0.f ? 1.0f / sqrtf(csum) : 0.f;
  float rc = r * cw[j];
  leftv[j] = l;
  rightc[j] = rc;
  mvec[j] = l * rc;   // inner-k diagonal factor
}

// ---------------- K4: gather seed columns into Bg[k][s] = g0[k][sid[s]] * m[k]
__global__ void k_gatherB(const float* __restrict__ g0, const int* __restrict__ sid,
                          const float* __restrict__ mvec, float* __restrict__ Bg) {
  int idx = blockIdx.x * 256 + threadIdx.x;
  int k = idx >> 9;           // /512
  int s = idx & (SDIM - 1);
  Bg[idx] = g0[(size_t)k * NDIM + sid[s]] * mvec[k];
}

// ---------------- K5: C[q][s] = left[qid]*rightc[sid] * sum_k g0[qid,k]*Bg[k,s]
#define TM 32
#define TN 64
#define BK 32
__global__ __launch_bounds__(256) void k_matmul(
    const float* __restrict__ g0, const float* __restrict__ Bg,
    const int* __restrict__ qid, const int* __restrict__ sid,
    const float* __restrict__ leftv, const float* __restrict__ rightc,
    float* __restrict__ C) {
  __shared__ __align__(16) float As[BK][TM + 2];   // [k][m], pad->34 (2-way bank alias: free)
  __shared__ __align__(16) float Bs[BK][TN + 4];   // [k][n], pad->68, float4-aligned rows
  __shared__ int qrow[TM]; __shared__ float lq[TM];
  __shared__ int srow[TN]; __shared__ float rsc[TN];
  int t = threadIdx.x;
  int bx = blockIdx.x;   // s-block 0..7
  int by = blockIdx.y;   // q-block 0..31
  if (t < TM) { int r = qid[by * TM + t]; qrow[t] = r; lq[t] = leftv[r]; }
  else if (t < TM + TN) { int i = t - TM; int c = sid[bx * TN + i]; srow[i] = c; rsc[i] = rightc[c]; }
  __syncthreads();
  int tx = t & 15, ty = t >> 4;
  float acc[2][4] = {};
  for (int k0 = 0; k0 < NDIM; k0 += BK) {
    #pragma unroll
    for (int p = 0; p < 4; p++) {            // A tile: 32x32
      int l = t + p * 256;
      int i = l >> 5, kk = l & 31;           // consecutive t -> consecutive kk (coalesced)
      As[kk][i] = g0[(size_t)qrow[i] * NDIM + k0 + kk];
    }
    #pragma unroll
    for (int p = 0; p < 8; p++) {            // B tile: 32x64
      int l = t + p * 256;
      int kk = l >> 6, n = l & 63;
      Bs[kk][n] = Bg[(size_t)(k0 + kk) * SDIM + bx * TN + n];
    }
    __syncthreads();
    #pragma unroll
    for (int kk = 0; kk < BK; kk++) {
      float2 a = *(const float2*)&As[kk][ty * 2];
      float4 b = *(const float4*)&Bs[kk][tx * 4];
      acc[0][0] += a.x * b.x; acc[0][1] += a.x * b.y; acc[0][2] += a.x * b.z; acc[0][3] += a.x * b.w;
      acc[1][0] += a.y * b.x; acc[1][1] += a.y * b.y; acc[1][2] += a.y * b.z; acc[1][3] += a.y * b.w;
    }
    __syncthreads();
  }
  #pragma unroll
  for (int r = 0; r < 2; r++) {
    int m = ty * 2 + r;
    int qg = by * TM + m;
    int qi = qrow[m];
    float lf = lq[m];
    float4 v4;
    float* vp = (float*)&v4;
    #pragma unroll
    for (int c = 0; c < 4; c++) {
      int n = tx * 4 + c;
      float v = acc[r][c] * lf * rsc[n];
      if (srow[n] == qi) v = 0.f;            // diag mask: seed==query
      vp[c] = v;
    }
    *(float4*)&C[(size_t)qg * SDIM + bx * TN + tx * 4] = v4;
  }
}

// ---------------- K6: stats over C (sum, sumsq, count of >0) in fp64
__global__ void k_stats(const float* __restrict__ C, double* __restrict__ stats) {
  __shared__ float r1[256], r2[256]; __shared__ int rc[256];
  int t = threadIdx.x;
  size_t base = (size_t)blockIdx.x * 1024 + t;
  float s = 0.f, s2 = 0.f; int c = 0;
  #pragma unroll
  for (int p = 0; p < 4; p++) {
    float x = C[base + p * 256];
    if (x > 0.f) { s += x; s2 += x * x; c++; }
  }
  r1[t] = s; r2[t] = s2; rc[t] = c; __syncthreads();
  for (int st = 128; st > 0; st >>= 1) {
    if (t < st) { r1[t] += r1[t+st]; r2[t] += r2[t+st]; rc[t] += rc[t+st]; }
    __syncthreads();
  }
  if (t == 0) {
    atomicAdd(&stats[0], (double)r1[0]);
    atomicAdd(&stats[1], (double)r2[0]);
    atomicAdd(&stats[2], (double)rc[0]);
  }
}

// ---------------- K7: global calib + row-normalize (one block per query row)
__global__ void k_final(const float* __restrict__ C, const double* __restrict__ stats,
                        const float* __restrict__ gw, const float* __restrict__ gb,
                        float* __restrict__ out) {
  __shared__ float red[256];
  int q = blockIdx.x, t = threadIdx.x;
  double mean_d = stats[0] / stats[2];
  double var_d = stats[1] / stats[2] - mean_d * mean_d;
  float mean = (float)mean_d;
  float invstd = (float)(1.0 / sqrt(var_d));
  float w0 = gw[0], w1 = gw[1], w2 = gw[2], w3 = gw[3], w4 = gw[4], bb = gb[0];
  float vals[2]; float rs = 0.f;
  #pragma unroll
  for (int p = 0; p < 2; p++) {
    int s = t + p * 256;
    float x = C[(size_t)q * SDIM + s];
    float v = 0.f;
    if (x > 0.f) {
      float gn = (x - mean) * invstd;
      float m = fabsf(gn);
      float sgnsq = (m > 0.f) ? (gn / m) * sqrtf(m) : 0.f;  // sign(gn)*sqrt(|gn|)
      float acc = w0 * gn + w1 * sgnsq;
      float gm = gn * m; acc += w2 * gm;   // gn*|gn|
      gm *= m;           acc += w3 * gm;   // gn*|gn|^2
      gm *= m;           acc += w4 * gm;   // gn*|gn|^3
      acc += bb;
      v = (acc > 0.f ? acc : __expf(acc) - 1.f) + 1.f;  // elu + 1
    }
    vals[p] = v; rs += v;
  }
  red[t] = rs; __syncthreads();
  for (int st = 128; st > 0; st >>= 1) { if (t < st) red[t] += red[t+st]; __syncthreads(); }
  float tot = red[0];
  float inv = tot > 0.f ? 1.0f / tot : 0.f;   // divide_no_nan
  #pragma unroll
  for (int p = 0; p < 2; p++) {
    int s = t + p * 256;
    out[(size_t)q * SDIM + s] = vals[p] * inv;
  }
}

extern "C" void kernel_launch(void* const* d_in, const int* in_sizes, int n_in,
                              void* d_out, int out_size, void* d_ws, size_t ws_size,
                              hipStream_t stream) {
  const float* graph    = (const float*)d_in[0];
  const float* calib_w  = (const float*)d_in[1];
  const float* global_w = (const float*)d_in[2];
  const float* global_b = (const float*)d_in[3];
  const float* col_w    = (const float*)d_in[4];
  const int*   qid      = (const int*)d_in[5];
  const int*   sid      = (const int*)d_in[6];
  float* out = (float*)d_out;

  char* ws = (char*)d_ws;
  float*  probs  = (float*)(ws + 0);        // 20 f
  float*  cw     = (float*)(ws + 128);      // 2048 f
  float*  rowsum = (float*)(ws + 8320);     // 2048 f
  float*  colsum = (float*)(ws + 16512);    // 2048 f
  float*  leftv  = (float*)(ws + 24704);    // 2048 f
  float*  rightc = (float*)(ws + 32896);    // 2048 f
  float*  mvec   = (float*)(ws + 41088);    // 2048 f
  double* stats  = (double*)(ws + 49280);   // 3 d
  float*  g0     = (float*)(ws + 65536);                         // N*N f = 16 MiB
  float*  Bg     = (float*)(ws + 65536 + 16777216);              // N*S f = 4 MiB
  float*  C      = (float*)(ws + 65536 + 16777216 + 4194304);    // Q*S f = 2 MiB

  hipMemsetAsync(colsum, 0, NDIM * sizeof(float), stream);
  hipMemsetAsync(stats, 0, 3 * sizeof(double), stream);

  k_prep<<<1, 256, 0, stream>>>(calib_w, col_w, probs, cw);
  k_calib<<<NDIM, 256, 0, stream>>>(graph, probs, g0, rowsum);
  k_colsum<<<dim3(8, 16), 256, 0, stream>>>(g0, colsum);
  k_factors<<<NDIM / 256, 256, 0, stream>>>(rowsum, colsum, cw, leftv, rightc, mvec);
  k_gatherB<<<(NDIM * SDIM) / 256, 256, 0, stream>>>(g0, sid, mvec, Bg);
  k_matmul<<<dim3(SDIM / TN, QDIM / TM), 256, 0, stream>>>(g0, Bg, qid, sid, leftv, rightc, C);
  k_stats<<<512, 256, 0, stream>>>(C, stats);
  k_final<<<QDIM, 256, 0, stream>>>(C, stats, global_w, global_b, out);
}

// Round 2
// 178.657 us; speedup vs baseline: 1.2883x; 1.2883x over previous
//
#include <hip/hip_runtime.h>
#include <hip/hip_bf16.h>

#define NDIM 2048
#define QDIM 1024
#define SDIM 512
#define NBINS 20

typedef __attribute__((ext_vector_type(8))) short bf16x8;
typedef __attribute__((ext_vector_type(4))) float f32x4;

__device__ __forceinline__ unsigned short f2bf(float f) {
  unsigned int u = __builtin_bit_cast(unsigned int, f);
  u += 0x7fffu + ((u >> 16) & 1u);   // round-to-nearest-even (no NaN in this data)
  return (unsigned short)(u >> 16);
}

// ---------------- K0: softmax prep (probs over calib_w, cw over col_weights)
__global__ void k_prep(const float* __restrict__ calib_w,
                       const float* __restrict__ col_w,
                       float* __restrict__ probs,
                       float* __restrict__ cw) {
  __shared__ float red[256];
  int t = threadIdx.x;
  if (t == 0) {
    float m = -1e30f;
    for (int b = 0; b < NBINS; b++) m = fmaxf(m, calib_w[b]);
    float e[NBINS]; float s = 0.f;
    for (int b = 0; b < NBINS; b++) { e[b] = __expf(calib_w[b] - m); s += e[b]; }
    float inv = 1.0f / s;
    for (int b = 0; b < NBINS; b++) probs[b] = e[b] * inv;
  }
  float lm = -1e30f;
  for (int j = t; j < NDIM; j += 256) lm = fmaxf(lm, col_w[j]);
  red[t] = lm; __syncthreads();
  for (int s = 128; s > 0; s >>= 1) { if (t < s) red[t] = fmaxf(red[t], red[t+s]); __syncthreads(); }
  float gmax = red[0]; __syncthreads();
  float ls = 0.f;
  for (int j = t; j < NDIM; j += 256) ls += __expf(col_w[j] - gmax);
  red[t] = ls; __syncthreads();
  for (int s = 128; s > 0; s >>= 1) { if (t < s) red[t] += red[t+s]; __syncthreads(); }
  float scale = (float)NDIM / red[0];
  for (int j = t; j < NDIM; j += 256) cw[j] = __expf(col_w[j] - gmax) * scale;
}

// ---------------- K1: local calibration (one block per row) + row sums
__global__ __launch_bounds__(256) void k_calib(const float* __restrict__ graph,
                                               const float* __restrict__ probs,
                                               float* __restrict__ g0,
                                               float* __restrict__ rowsum) {
  __shared__ float sp[NBINS];
  __shared__ float red[256];
  int i = blockIdx.x, t = threadIdx.x;
  if (t < NBINS) sp[t] = probs[t];
  __syncthreads();
  const float* row = graph + (size_t)i * NDIM;
  float* orow = g0 + (size_t)i * NDIM;
  float rs = 0.f;
  for (int it = 0; it < NDIM / 256; it++) {
    int j = t + it * 256;
    float g = row[j];
    float v = 0.f;
    if (g > 0.f) {
      float num = 0.f, den = 0.f;
      #pragma unroll
      for (int b = 0; b < NBINS; b++) {
        float d = g - (float)b * (1.0f / 19.0f);
        float z = __expf(-950.0f * d * d);   // sig = (1/19)/50 = 1/950 for all bins
        den += z; num += z * sp[b];
      }
      v = den > 0.f ? num / den : 0.f;
    }
    orow[j] = v;
    rs += v;
  }
  red[t] = rs; __syncthreads();
  for (int s = 128; s > 0; s >>= 1) { if (t < s) red[t] += red[t+s]; __syncthreads(); }
  if (t == 0) rowsum[i] = red[0];
}

// ---------------- K2: column sums of g0
__global__ void k_colsum(const float* __restrict__ g0, float* __restrict__ colsum) {
  int j = blockIdx.x * 256 + threadIdx.x;   // gridDim.x = 8
  int r0 = blockIdx.y * 128;                // gridDim.y = 16
  float s = 0.f;
  for (int r = r0; r < r0 + 128; r++) s += g0[(size_t)r * NDIM + j];
  atomicAdd(&colsum[j], s);
}

// ---------------- K3: per-row/col scale factors
__global__ void k_factors(const float* __restrict__ rowsum, const float* __restrict__ colsum,
                          const float* __restrict__ cw,
                          float* __restrict__ leftv, float* __restrict__ rightc,
                          float* __restrict__ mvec) {
  int j = blockIdx.x * 256 + threadIdx.x;
  float rsum = rowsum[j], csum = colsum[j];
  float l = rsum > 0.f ? 1.0f / sqrtf(rsum) : 0.f;   // divide_no_nan(1, sqrt(.))
  float r = csum > 0.f ? 1.0f / sqrtf(csum) : 0.f;
  float rc = r * cw[j];
  leftv[j] = l;
  rightc[j] = rc;
  mvec[j] = l * rc;   // inner-k diagonal factor
}

// ---------------- K4a: gathered A panel, bf16, leftv folded: Aq[q][k] = g0[qid[q]][k]*leftv
__global__ void k_gatherA(const float* __restrict__ g0, const int* __restrict__ qid,
                          const float* __restrict__ leftv, unsigned short* __restrict__ Aq) {
  int q = blockIdx.x, t = threadIdx.x;
  int row = qid[q];
  float lf = leftv[row];
  const float4* src = (const float4*)(g0 + (size_t)row * NDIM);
  float4 v0 = src[t * 2];
  float4 v1 = src[t * 2 + 1];
  unsigned short tmp[8];
  tmp[0] = f2bf(v0.x * lf); tmp[1] = f2bf(v0.y * lf);
  tmp[2] = f2bf(v0.z * lf); tmp[3] = f2bf(v0.w * lf);
  tmp[4] = f2bf(v1.x * lf); tmp[5] = f2bf(v1.y * lf);
  tmp[6] = f2bf(v1.z * lf); tmp[7] = f2bf(v1.w * lf);
  uint4 packed;
  __builtin_memcpy(&packed, tmp, 16);
  *(uint4*)(Aq + (size_t)q * NDIM + t * 8) = packed;
}

// ---------------- K4b: transposed B panel, bf16: Bt[s][k] = g0[k][sid[s]]*mvec[k]*rightc[sid[s]]
__global__ void k_gatherBt(const float* __restrict__ g0, const int* __restrict__ sid,
                           const float* __restrict__ mvec, const float* __restrict__ rightc,
                           unsigned short* __restrict__ Bt) {
  int s = blockIdx.x, t = threadIdx.x;
  int col = sid[s];
  float rsc = rightc[col];
  unsigned short* dst = Bt + (size_t)s * NDIM;
  #pragma unroll
  for (int i = 0; i < 8; i++) {
    int k = i * 256 + t;
    float v = g0[(size_t)k * NDIM + col] * mvec[k] * rsc;
    dst[k] = f2bf(v);
  }
}

// ---------------- K5: C_partial[kc] = Aq(64x512-chunk) x Bt^T via MFMA 16x16x32 bf16
// wave = 32x32 (2x2 frags), block = 4 waves = 64x64 tile, split-K 4
__global__ __launch_bounds__(256) void k_mfma(const unsigned short* __restrict__ Aq,
                                              const unsigned short* __restrict__ Bt,
                                              float* __restrict__ Cp) {
  int t = threadIdx.x;
  int lane = t & 63;
  int wave = t >> 6;
  int m0 = blockIdx.y * 64 + (wave >> 1) * 32;
  int n0 = blockIdx.x * 64 + (wave & 1) * 32;
  int kc = blockIdx.z;
  int fr = lane & 15;            // A-row / B-col within 16-tile
  int kq = (lane >> 4) * 8;      // k-quad offset
  const unsigned short* Ap0 = Aq + (size_t)(m0 + fr) * NDIM + kc * 512 + kq;
  const unsigned short* Ap1 = Ap0 + (size_t)16 * NDIM;
  const unsigned short* Bp0 = Bt + (size_t)(n0 + fr) * NDIM + kc * 512 + kq;
  const unsigned short* Bp1 = Bp0 + (size_t)16 * NDIM;
  f32x4 acc00 = {0.f,0.f,0.f,0.f}, acc01 = acc00, acc10 = acc00, acc11 = acc00;
  #pragma unroll 4
  for (int i = 0; i < 16; i++) {
    int off = i * 32;
    bf16x8 a0 = *(const bf16x8*)(Ap0 + off);
    bf16x8 a1 = *(const bf16x8*)(Ap1 + off);
    bf16x8 b0 = *(const bf16x8*)(Bp0 + off);
    bf16x8 b1 = *(const bf16x8*)(Bp1 + off);
    acc00 = __builtin_amdgcn_mfma_f32_16x16x32_bf16(a0, b0, acc00, 0, 0, 0);
    acc01 = __builtin_amdgcn_mfma_f32_16x16x32_bf16(a0, b1, acc01, 0, 0, 0);
    acc10 = __builtin_amdgcn_mfma_f32_16x16x32_bf16(a1, b0, acc10, 0, 0, 0);
    acc11 = __builtin_amdgcn_mfma_f32_16x16x32_bf16(a1, b1, acc11, 0, 0, 0);
  }
  // C/D layout: col = lane&15, row = (lane>>4)*4 + reg   [m89-verified]
  float* Cb = Cp + ((size_t)kc << 19);   // kc * QDIM * SDIM
  int r0 = (lane >> 4) * 4;
  int c0 = lane & 15;
  #pragma unroll
  for (int r = 0; r < 4; r++) {
    Cb[(size_t)(m0 + r0 + r) * SDIM + n0 + c0]           = acc00[r];
    Cb[(size_t)(m0 + r0 + r) * SDIM + n0 + 16 + c0]      = acc01[r];
    Cb[(size_t)(m0 + 16 + r0 + r) * SDIM + n0 + c0]      = acc10[r];
    Cb[(size_t)(m0 + 16 + r0 + r) * SDIM + n0 + 16 + c0] = acc11[r];
  }
}

// ---------------- K6: reduce 4 partials + diag mask + write C + global stats
__global__ void k_reduce_stats(const float* __restrict__ Cp,
                               const int* __restrict__ qid, const int* __restrict__ sid,
                               float* __restrict__ C, double* __restrict__ stats) {
  __shared__ float r1[256], r2[256]; __shared__ int rc[256];
  int t = threadIdx.x;
  int idx4 = blockIdx.x * 256 + t;                 // float4 index, 512 blocks
  const float4* Cp4 = (const float4*)Cp;
  const int STRIDE4 = QDIM * SDIM / 4;             // 131072
  float4 v = Cp4[idx4];
  float4 v1 = Cp4[idx4 + STRIDE4];
  float4 v2 = Cp4[idx4 + 2 * STRIDE4];
  float4 v3 = Cp4[idx4 + 3 * STRIDE4];
  v.x += v1.x + v2.x + v3.x; v.y += v1.y + v2.y + v3.y;
  v.z += v1.z + v2.z + v3.z; v.w += v1.w + v2.w + v3.w;
  int base = idx4 * 4;
  int q = base >> 9;
  int s0 = base & (SDIM - 1);
  int qv = qid[q];
  if (sid[s0]     == qv) v.x = 0.f;
  if (sid[s0 + 1] == qv) v.y = 0.f;
  if (sid[s0 + 2] == qv) v.z = 0.f;
  if (sid[s0 + 3] == qv) v.w = 0.f;
  ((float4*)C)[idx4] = v;
  float s = 0.f, s2 = 0.f; int c = 0;
  float* vp = (float*)&v;
  #pragma unroll
  for (int p = 0; p < 4; p++) {
    float x = vp[p];
    if (x > 0.f) { s += x; s2 += x * x; c++; }
  }
  r1[t] = s; r2[t] = s2; rc[t] = c; __syncthreads();
  for (int st = 128; st > 0; st >>= 1) {
    if (t < st) { r1[t] += r1[t+st]; r2[t] += r2[t+st]; rc[t] += rc[t+st]; }
    __syncthreads();
  }
  if (t == 0) {
    atomicAdd(&stats[0], (double)r1[0]);
    atomicAdd(&stats[1], (double)r2[0]);
    atomicAdd(&stats[2], (double)rc[0]);
  }
}

// ---------------- K7: global calib + row-normalize (one block per query row)
__global__ void k_final(const float* __restrict__ C, const double* __restrict__ stats,
                        const float* __restrict__ gw, const float* __restrict__ gb,
                        float* __restrict__ out) {
  __shared__ float red[256];
  int q = blockIdx.x, t = threadIdx.x;
  double mean_d = stats[0] / stats[2];
  double var_d = stats[1] / stats[2] - mean_d * mean_d;
  float mean = (float)mean_d;
  float invstd = (float)(1.0 / sqrt(var_d));
  float w0 = gw[0], w1 = gw[1], w2 = gw[2], w3 = gw[3], w4 = gw[4], bb = gb[0];
  float vals[2]; float rs = 0.f;
  #pragma unroll
  for (int p = 0; p < 2; p++) {
    int s = t + p * 256;
    float x = C[(size_t)q * SDIM + s];
    float v = 0.f;
    if (x > 0.f) {
      float gn = (x - mean) * invstd;
      float m = fabsf(gn);
      float sgnsq = (m > 0.f) ? (gn / m) * sqrtf(m) : 0.f;  // sign(gn)*sqrt(|gn|)
      float acc = w0 * gn + w1 * sgnsq;
      float gm = gn * m; acc += w2 * gm;   // gn*|gn|
      gm *= m;           acc += w3 * gm;   // gn*|gn|^2
      gm *= m;           acc += w4 * gm;   // gn*|gn|^3
      acc += bb;
      v = (acc > 0.f ? acc : __expf(acc) - 1.f) + 1.f;  // elu + 1
    }
    vals[p] = v; rs += v;
  }
  red[t] = rs; __syncthreads();
  for (int st = 128; st > 0; st >>= 1) { if (t < st) red[t] += red[t+st]; __syncthreads(); }
  float tot = red[0];
  float inv = tot > 0.f ? 1.0f / tot : 0.f;   // divide_no_nan
  #pragma unroll
  for (int p = 0; p < 2; p++) {
    int s = t + p * 256;
    out[(size_t)q * SDIM + s] = vals[p] * inv;
  }
}

extern "C" void kernel_launch(void* const* d_in, const int* in_sizes, int n_in,
                              void* d_out, int out_size, void* d_ws, size_t ws_size,
                              hipStream_t stream) {
  const float* graph    = (const float*)d_in[0];
  const float* calib_w  = (const float*)d_in[1];
  const float* global_w = (const float*)d_in[2];
  const float* global_b = (const float*)d_in[3];
  const float* col_w    = (const float*)d_in[4];
  const int*   qid      = (const int*)d_in[5];
  const int*   sid      = (const int*)d_in[6];
  float* out = (float*)d_out;

  char* ws = (char*)d_ws;
  float*  probs  = (float*)(ws + 0);        // 20 f
  float*  cw     = (float*)(ws + 128);      // 2048 f
  float*  rowsum = (float*)(ws + 8320);     // 2048 f
  float*  colsum = (float*)(ws + 16512);    // 2048 f
  float*  leftv  = (float*)(ws + 24704);    // 2048 f
  float*  rightc = (float*)(ws + 32896);    // 2048 f
  float*  mvec   = (float*)(ws + 41088);    // 2048 f
  double* stats  = (double*)(ws + 49280);   // 3 d
  // g0 occupies [64K, 64K+16M); after the gathers it is dead, so the MFMA
  // partials (8 MB) and final C (2 MB) alias its storage.
  float*  g0     = (float*)(ws + 65536);                         // N*N f = 16 MiB
  float*  Cp     = (float*)(ws + 65536);                         // 4*Q*S f = 8 MiB (aliases g0)
  float*  C      = (float*)(ws + 65536 + 8388608);               // Q*S f = 2 MiB (aliases g0)
  unsigned short* Aq = (unsigned short*)(ws + 65536 + 16777216);             // Q*N bf16 = 4 MiB
  unsigned short* Bt = (unsigned short*)(ws + 65536 + 16777216 + 4194304);   // S*N bf16 = 2 MiB

  hipMemsetAsync(colsum, 0, NDIM * sizeof(float), stream);
  hipMemsetAsync(stats, 0, 3 * sizeof(double), stream);

  k_prep<<<1, 256, 0, stream>>>(calib_w, col_w, probs, cw);
  k_calib<<<NDIM, 256, 0, stream>>>(graph, probs, g0, rowsum);
  k_colsum<<<dim3(8, 16), 256, 0, stream>>>(g0, colsum);
  k_factors<<<NDIM / 256, 256, 0, stream>>>(rowsum, colsum, cw, leftv, rightc, mvec);
  k_gatherA<<<QDIM, 256, 0, stream>>>(g0, qid, leftv, Aq);
  k_gatherBt<<<SDIM, 256, 0, stream>>>(g0, sid, mvec, rightc, Bt);
  k_mfma<<<dim3(SDIM / 64, QDIM / 64, 4), 256, 0, stream>>>(Aq, Bt, Cp);
  k_reduce_stats<<<QDIM * SDIM / 1024, 256, 0, stream>>>(Cp, qid, sid, C, stats);
  k_final<<<QDIM, 256, 0, stream>>>(C, stats, global_w, global_b, out);
}